// Round 1
// baseline (76.591 us; speedup 1.0000x reference)
//
#include <hip/hip_runtime.h>

typedef __attribute__((ext_vector_type(4))) float f32x4;
typedef __attribute__((ext_vector_type(8))) short bf16x8;

#define NP 4096
#define IB 4

__device__ __forceinline__ unsigned short f2bf(float f) {
  unsigned int u = __float_as_uint(f);
  u = u + 0x7FFFu + ((u >> 16) & 1u);   // round-to-nearest-even
  return (unsigned short)(u >> 16);
}

__global__ __launch_bounds__(256) void prep_kernel(
    const float2* __restrict__ pos, const float2* __restrict__ past,
    float4* __restrict__ posvel) {
  int i = blockIdx.x * 256 + threadIdx.x;
  float2 p = pos[i];
  float2 q = past[i];
  posvel[i] = make_float4(p.x, p.y, p.x - q.x, p.y - q.y);
}

// Each block handles IB consecutive pedestrians i; accumulates per-i 16x16 grid
// of (sum_vx, sum_vy, count) in LDS. Layout acc[cell*13 + i_local*3 + c]
// (stride 13 coprime with 32 banks).
__global__ __launch_bounds__(256) void pool_kernel(
    const float4* __restrict__ posvel, unsigned short* __restrict__ gridws) {
  __shared__ float acc[256 * 13];
  const int tid = threadIdx.x;
  const int tx = tid & (IB - 1);   // i_local
  const int ty = tid >> 2;         // j group (0..63)
  const int ibase = blockIdx.x * IB;
  const int i = ibase + tx;

  for (int idx = tid; idx < 256 * 13; idx += 256) acc[idx] = 0.0f;
  __syncthreads();

  const float4 pvi = posvel[i];
  const int mybase = tx * 3;

  for (int j = ty; j < NP; j += 64) {
    float4 pvj = posvel[j];
    float rx = pvj.x - pvi.x;
    float ry = pvj.y - pvi.y;
    // exact IEEE fp32 division to match numpy's floor(rel/0.6 + 8)
    float fx = floorf(rx / 0.6f + 8.0f);
    float fy = floorf(ry / 0.6f + 8.0f);
    bool ok = (fx >= 0.0f) & (fx < 16.0f) & (fy >= 0.0f) & (fy < 16.0f) & (j != i);
    if (ok) {
      int cell = ((int)fx << 4) + (int)fy;
      float* p = &acc[cell * 13 + mybase];
      atomicAdd(p + 0, pvj.z - pvi.z);
      atomicAdd(p + 1, pvj.w - pvi.w);
      atomicAdd(p + 2, 1.0f);
    }
  }
  __syncthreads();

  // epilogue: normalize (mean per cell) and store bf16 grid row-major [NP][512]
  const int cell = tid;  // 0..255
#pragma unroll
  for (int il = 0; il < IB; ++il) {
    float sx = acc[cell * 13 + il * 3 + 0];
    float sy = acc[cell * 13 + il * 3 + 1];
    float cn = acc[cell * 13 + il * 3 + 2];
    float d = fmaxf(cn, 1.0f);
    unsigned int packed =
        ((unsigned int)f2bf(sy / d) << 16) | (unsigned int)f2bf(sx / d);
    *(unsigned int*)&gridws[(size_t)(ibase + il) * 512 + cell * 2] = packed;
  }
}

// C[4096][256] = relu(A[4096][512](bf16) * W[256][512]^T + b), fp32 out.
// 64x64 tile per block, 4 waves in 2x2 quadrants, each wave 2x2 MFMA frags.
__global__ __launch_bounds__(256) void gemm_kernel(
    const unsigned short* __restrict__ A, const float* __restrict__ W,
    const float* __restrict__ bias, float* __restrict__ out) {
  __shared__ unsigned short As[64][32];
  __shared__ unsigned short Bs[64][32];
  const int tid = threadIdx.x;
  const int lane = tid & 63;
  const int wid = tid >> 6;
  const int wr = wid >> 1;
  const int wc = wid & 1;
  const int mbase = blockIdx.y * 64;
  const int nbase = blockIdx.x * 64;
  const int srow = tid >> 2;  // staging row 0..63
  const int skq = tid & 3;    // staging k-octet

  f32x4 acc00 = {0.f, 0.f, 0.f, 0.f};
  f32x4 acc01 = {0.f, 0.f, 0.f, 0.f};
  f32x4 acc10 = {0.f, 0.f, 0.f, 0.f};
  f32x4 acc11 = {0.f, 0.f, 0.f, 0.f};

  const int lrow = lane & 15;
  const int lk = (lane >> 4) * 8;

  for (int kb = 0; kb < 512; kb += 32) {
    __syncthreads();
    // stage A tile (already bf16): 16B per thread
    *(bf16x8*)&As[srow][skq * 8] =
        *(const bf16x8*)&A[(size_t)(mbase + srow) * 512 + kb + skq * 8];
    // stage B tile: convert W fp32 -> bf16
    const float* wp = &W[(size_t)(nbase + srow) * 512 + kb + skq * 8];
    float4 w0 = *(const float4*)wp;
    float4 w1 = *(const float4*)(wp + 4);
    bf16x8 bv;
    bv[0] = (short)f2bf(w0.x); bv[1] = (short)f2bf(w0.y);
    bv[2] = (short)f2bf(w0.z); bv[3] = (short)f2bf(w0.w);
    bv[4] = (short)f2bf(w1.x); bv[5] = (short)f2bf(w1.y);
    bv[6] = (short)f2bf(w1.z); bv[7] = (short)f2bf(w1.w);
    *(bf16x8*)&Bs[srow][skq * 8] = bv;
    __syncthreads();

    bf16x8 a0 = *(const bf16x8*)&As[wr * 32 + lrow][lk];
    bf16x8 a1 = *(const bf16x8*)&As[wr * 32 + 16 + lrow][lk];
    bf16x8 b0 = *(const bf16x8*)&Bs[wc * 32 + lrow][lk];
    bf16x8 b1 = *(const bf16x8*)&Bs[wc * 32 + 16 + lrow][lk];
    acc00 = __builtin_amdgcn_mfma_f32_16x16x32_bf16(a0, b0, acc00, 0, 0, 0);
    acc01 = __builtin_amdgcn_mfma_f32_16x16x32_bf16(a0, b1, acc01, 0, 0, 0);
    acc10 = __builtin_amdgcn_mfma_f32_16x16x32_bf16(a1, b0, acc10, 0, 0, 0);
    acc11 = __builtin_amdgcn_mfma_f32_16x16x32_bf16(a1, b1, acc11, 0, 0, 0);
  }

  // epilogue: D row = (lane>>4)*4 + q, col = lane&15 within each 16x16 frag
  const int row0 = mbase + wr * 32 + (lane >> 4) * 4;
  const int col0 = nbase + wc * 32 + lrow;
#pragma unroll
  for (int ni = 0; ni < 2; ++ni) {
    int col = col0 + ni * 16;
    float bv = bias[col];
    const f32x4* a0p = (ni == 0) ? &acc00 : &acc01;
    const f32x4* a1p = (ni == 0) ? &acc10 : &acc11;
#pragma unroll
    for (int q = 0; q < 4; ++q) {
      float v0 = (*a0p)[q] + bv;
      out[(size_t)(row0 + q) * 256 + col] = fmaxf(v0, 0.0f);
      float v1 = (*a1p)[q] + bv;
      out[(size_t)(row0 + 16 + q) * 256 + col] = fmaxf(v1, 0.0f);
    }
  }
}

extern "C" void kernel_launch(void* const* d_in, const int* in_sizes, int n_in,
                              void* d_out, int out_size, void* d_ws, size_t ws_size,
                              hipStream_t stream) {
  // inputs: 0=h (unused), 1=positions, 2=past_positions, 3=W_emb, 4=b_emb
  const float2* pos = (const float2*)d_in[1];
  const float2* past = (const float2*)d_in[2];
  const float* W = (const float*)d_in[3];
  const float* bias = (const float*)d_in[4];
  float* out = (float*)d_out;

  float4* posvel = (float4*)d_ws;
  unsigned short* gridws =
      (unsigned short*)((char*)d_ws + (size_t)NP * sizeof(float4));

  prep_kernel<<<NP / 256, 256, 0, stream>>>(pos, past, posvel);
  pool_kernel<<<NP / IB, 256, 0, stream>>>(posvel, gridws);
  dim3 g(256 / 64, NP / 64);
  gemm_kernel<<<g, 256, 0, stream>>>(gridws, W, bias, out);
}

// Round 2
// 74.909 us; speedup vs baseline: 1.0224x; 1.0224x over previous
//
#include <hip/hip_runtime.h>

typedef __attribute__((ext_vector_type(4))) float f32x4;
typedef __attribute__((ext_vector_type(8))) short bf16x8;

#define NP 4096
#define IB 2
#define ACC_STRIDE 7  // IB*3 + 1, coprime with 32 banks

__device__ __forceinline__ unsigned short f2bf(float f) {
  unsigned int u = __float_as_uint(f);
  u = u + 0x7FFFu + ((u >> 16) & 1u);   // round-to-nearest-even
  return (unsigned short)(u >> 16);
}

__global__ __launch_bounds__(256) void prep_kernel(
    const float2* __restrict__ pos, const float2* __restrict__ past,
    float4* __restrict__ posvel) {
  int i = blockIdx.x * 256 + threadIdx.x;
  float2 p = pos[i];
  float2 q = past[i];
  posvel[i] = make_float4(p.x, p.y, p.x - q.x, p.y - q.y);
}

// Each block handles IB consecutive pedestrians i; accumulates per-i 16x16 grid
// of (sum_vx, sum_vy, count) in LDS via ds_add_f32.
// Self-pair (j==i) is NOT branched out: it lands in cell 136 (8,8) adding
// vals (0,0) and count 1; compensated exactly in the epilogue.
__global__ __launch_bounds__(256, 8) void pool_kernel(
    const float4* __restrict__ posvel, unsigned short* __restrict__ gridws) {
  __shared__ float acc[256 * ACC_STRIDE];
  const int tid = threadIdx.x;
  const int tx = tid & (IB - 1);        // i_local
  const int ty = tid >> 1;              // j group (0..127)
  const int ibase = blockIdx.x * IB;
  const int i = ibase + tx;

  for (int idx = tid; idx < 256 * ACC_STRIDE; idx += 256) acc[idx] = 0.0f;
  __syncthreads();

  const float4 pvi = posvel[i];
  const int mybase = tx * 3;

  auto process = [&](float4 pvj) {
    // exact IEEE fp32 division to match numpy floor(rel/0.6 + 8)
    float fx = floorf((pvj.x - pvi.x) / 0.6f + 8.0f);
    float fy = floorf((pvj.y - pvi.y) / 0.6f + 8.0f);
    int ix = (int)fx;
    int iy = (int)fy;
    if (((unsigned)ix < 16u) & ((unsigned)iy < 16u)) {
      float* p = &acc[((ix << 4) + iy) * ACC_STRIDE + mybase];
      atomicAdd(p + 0, pvj.z - pvi.z);
      atomicAdd(p + 1, pvj.w - pvi.w);
      atomicAdd(p + 2, 1.0f);
    }
  };

  // 32 j-iterations per thread, unrolled 4x with hoisted independent loads
  for (int jo = 0; jo < NP; jo += 4 * 128) {
    float4 pv0 = posvel[jo + ty];
    float4 pv1 = posvel[jo + 128 + ty];
    float4 pv2 = posvel[jo + 256 + ty];
    float4 pv3 = posvel[jo + 384 + ty];
    process(pv0);
    process(pv1);
    process(pv2);
    process(pv3);
  }
  __syncthreads();

  // epilogue: normalize (mean per cell) and store bf16 grid row-major [NP][512]
  const int cell = tid;  // 0..255
  const float selfc = (cell == 136) ? 1.0f : 0.0f;
#pragma unroll
  for (int il = 0; il < IB; ++il) {
    float sx = acc[cell * ACC_STRIDE + il * 3 + 0];
    float sy = acc[cell * ACC_STRIDE + il * 3 + 1];
    float cn = acc[cell * ACC_STRIDE + il * 3 + 2] - selfc;
    float d = fmaxf(cn, 1.0f);
    unsigned int packed =
        ((unsigned int)f2bf(sy / d) << 16) | (unsigned int)f2bf(sx / d);
    *(unsigned int*)&gridws[(size_t)(ibase + il) * 512 + cell * 2] = packed;
  }
}

// C[4096][256] = relu(A[4096][512](bf16) * W[256][512]^T + b), fp32 out.
// 64x64 tile per block, 4 waves in 2x2 quadrants, each wave 2x2 MFMA frags.
__global__ __launch_bounds__(256) void gemm_kernel(
    const unsigned short* __restrict__ A, const float* __restrict__ W,
    const float* __restrict__ bias, float* __restrict__ out) {
  __shared__ unsigned short As[64][32];
  __shared__ unsigned short Bs[64][32];
  const int tid = threadIdx.x;
  const int lane = tid & 63;
  const int wid = tid >> 6;
  const int wr = wid >> 1;
  const int wc = wid & 1;
  const int mbase = blockIdx.y * 64;
  const int nbase = blockIdx.x * 64;
  const int srow = tid >> 2;  // staging row 0..63
  const int skq = tid & 3;    // staging k-octet

  f32x4 acc00 = {0.f, 0.f, 0.f, 0.f};
  f32x4 acc01 = {0.f, 0.f, 0.f, 0.f};
  f32x4 acc10 = {0.f, 0.f, 0.f, 0.f};
  f32x4 acc11 = {0.f, 0.f, 0.f, 0.f};

  const int lrow = lane & 15;
  const int lk = (lane >> 4) * 8;

  for (int kb = 0; kb < 512; kb += 32) {
    __syncthreads();
    // stage A tile (already bf16): 16B per thread
    *(bf16x8*)&As[srow][skq * 8] =
        *(const bf16x8*)&A[(size_t)(mbase + srow) * 512 + kb + skq * 8];
    // stage B tile: convert W fp32 -> bf16
    const float* wp = &W[(size_t)(nbase + srow) * 512 + kb + skq * 8];
    float4 w0 = *(const float4*)wp;
    float4 w1 = *(const float4*)(wp + 4);
    bf16x8 bv;
    bv[0] = (short)f2bf(w0.x); bv[1] = (short)f2bf(w0.y);
    bv[2] = (short)f2bf(w0.z); bv[3] = (short)f2bf(w0.w);
    bv[4] = (short)f2bf(w1.x); bv[5] = (short)f2bf(w1.y);
    bv[6] = (short)f2bf(w1.z); bv[7] = (short)f2bf(w1.w);
    *(bf16x8*)&Bs[srow][skq * 8] = bv;
    __syncthreads();

    bf16x8 a0 = *(const bf16x8*)&As[wr * 32 + lrow][lk];
    bf16x8 a1 = *(const bf16x8*)&As[wr * 32 + 16 + lrow][lk];
    bf16x8 b0 = *(const bf16x8*)&Bs[wc * 32 + lrow][lk];
    bf16x8 b1 = *(const bf16x8*)&Bs[wc * 32 + 16 + lrow][lk];
    acc00 = __builtin_amdgcn_mfma_f32_16x16x32_bf16(a0, b0, acc00, 0, 0, 0);
    acc01 = __builtin_amdgcn_mfma_f32_16x16x32_bf16(a0, b1, acc01, 0, 0, 0);
    acc10 = __builtin_amdgcn_mfma_f32_16x16x32_bf16(a1, b0, acc10, 0, 0, 0);
    acc11 = __builtin_amdgcn_mfma_f32_16x16x32_bf16(a1, b1, acc11, 0, 0, 0);
  }

  // epilogue: D row = (lane>>4)*4 + q, col = lane&15 within each 16x16 frag
  const int row0 = mbase + wr * 32 + (lane >> 4) * 4;
  const int col0 = nbase + wc * 32 + lrow;
#pragma unroll
  for (int ni = 0; ni < 2; ++ni) {
    int col = col0 + ni * 16;
    float bv = bias[col];
    const f32x4* a0p = (ni == 0) ? &acc00 : &acc01;
    const f32x4* a1p = (ni == 0) ? &acc10 : &acc11;
#pragma unroll
    for (int q = 0; q < 4; ++q) {
      float v0 = (*a0p)[q] + bv;
      out[(size_t)(row0 + q) * 256 + col] = fmaxf(v0, 0.0f);
      float v1 = (*a1p)[q] + bv;
      out[(size_t)(row0 + 16 + q) * 256 + col] = fmaxf(v1, 0.0f);
    }
  }
}

extern "C" void kernel_launch(void* const* d_in, const int* in_sizes, int n_in,
                              void* d_out, int out_size, void* d_ws, size_t ws_size,
                              hipStream_t stream) {
  // inputs: 0=h (unused), 1=positions, 2=past_positions, 3=W_emb, 4=b_emb
  const float2* pos = (const float2*)d_in[1];
  const float2* past = (const float2*)d_in[2];
  const float* W = (const float*)d_in[3];
  const float* bias = (const float*)d_in[4];
  float* out = (float*)d_out;

  float4* posvel = (float4*)d_ws;
  unsigned short* gridws =
      (unsigned short*)((char*)d_ws + (size_t)NP * sizeof(float4));

  prep_kernel<<<NP / 256, 256, 0, stream>>>(pos, past, posvel);
  pool_kernel<<<NP / IB, 256, 0, stream>>>(posvel, gridws);
  dim3 g(256 / 64, NP / 64);
  gemm_kernel<<<g, 256, 0, stream>>>(gridws, W, bias, out);
}